// Round 3
// baseline (361.450 us; speedup 1.0000x reference)
//
#include <hip/hip_runtime.h>

// SSN soft-superpixel assignment. Fixed shapes: x (4,32,256,256) fp32, s=16.
// M = 0 -> the two grid channels are identically zero everywhere (px and
// centroids), so they cancel in distances and updates; drop them (C=32).
#define B_  4
#define C_  32
#define H_  256
#define W_  256
#define N_  65536   // H*W
#define NH_ 16      // 16x16 superpixel grid
#define S_  256
#define PADP 260    // padded pixel stride for LDS [c][p] / [k][p] tiles
#define PSTR 304    // per-block partial stride: 288 num + 9 den + pad

__device__ __forceinline__ float wave_sum(float v) {
    v += __shfl_down(v, 32);
    v += __shfl_down(v, 16);
    v += __shfl_down(v, 8);
    v += __shfl_down(v, 4);
    v += __shfl_down(v, 2);
    v += __shfl_down(v, 1);
    return v;  // lane 0 holds the 64-lane sum
}

// Stage this block's 16x16x32 tile of x into xsh[c][p] (p = py*16+px) with
// coalesced float4 loads: 8 per thread; per wave c is fixed, lanes cover the
// 64 float4 of one channel tile (16 rows x 64B segments).
__device__ __forceinline__ void stage_tile(const float* __restrict__ x,
                                           int b, int sy, int sx, int t,
                                           float (*xsh)[PADP]) {
    const float* base = x + (size_t)b * C_ * N_ + (sy * 16) * W_ + sx * 16;
    #pragma unroll
    for (int i = 0; i < 8; ++i) {
        const int idx = i * 256 + t;        // [0, 2048)
        const int c = idx >> 6, p4 = idx & 63;
        const int py = p4 >> 2, px4 = (p4 & 3) * 4;
        const float4 v = *(const float4*)(base + (size_t)c * N_ + py * W_ + px4);
        *(float4*)&xsh[c][p4 * 4] = v;
    }
}

// Per-pixel softmax over the 3x3 superpixel neighborhood. cl[k][c] is 0 for
// invalid k (masked to aff=0 anyway). Vectorized float4 broadcast reads of cl.
__device__ __forceinline__ void compute_aff(const float xv[C_], const float (*cl)[C_],
                                            int sy, int sx, float aff[9]) {
    float dist[9];
    #pragma unroll
    for (int k = 0; k < 9; ++k) {
        const int ny = sy + k / 3 - 1, nx = sx + k % 3 - 1;
        const bool valid = (ny >= 0) & (ny < NH_) & (nx >= 0) & (nx < NH_);
        float d = 0.f;
        #pragma unroll
        for (int c4 = 0; c4 < C_ / 4; ++c4) {
            const float4 cv = *(const float4*)&cl[k][c4 * 4];   // LDS broadcast b128
            const float d0 = xv[c4 * 4 + 0] - cv.x;
            const float d1 = xv[c4 * 4 + 1] - cv.y;
            const float d2 = xv[c4 * 4 + 2] - cv.z;
            const float d3 = xv[c4 * 4 + 3] - cv.w;
            d += d0 * d0 + d1 * d1 + d2 * d2 + d3 * d3;
        }
        dist[k] = valid ? d : 1e30f;
    }
    float mind = dist[0];
    #pragma unroll
    for (int k = 1; k < 9; ++k) mind = fminf(mind, dist[k]);
    float sum = 0.f;
    #pragma unroll
    for (int k = 0; k < 9; ++k) {
        const float e = (dist[k] < 1e29f) ? __expf(mind - dist[k]) : 0.f;
        aff[k] = e;
        sum += e;
    }
    const float inv = 1.f / sum;   // home superpixel always valid -> sum > 0
    #pragma unroll
    for (int k = 0; k < 9; ++k) aff[k] *= inv;
}

// Fill cl[9][32] from cent (288 entries, 256 threads: k=8 done by t<32).
__device__ __forceinline__ void load_cl(const float* __restrict__ cent,
                                        int b, int sy, int sx, int t,
                                        float (*cl)[C_]) {
    {
        const int k = t >> 5, c = t & 31;
        const int ny = sy + k / 3 - 1, nx = sx + k % 3 - 1;
        const bool valid = (ny >= 0) & (ny < NH_) & (nx >= 0) & (nx < NH_);
        cl[k][c] = valid ? cent[(size_t)(b * S_ + ny * NH_ + nx) * C_ + c] : 0.f;
    }
    if (t < 32) {
        const int ny = sy + 1, nx = sx + 1;   // k = 8
        const bool valid = (ny < NH_) & (nx < NH_);
        cl[8][t] = valid ? cent[(size_t)(b * S_ + ny * NH_ + nx) * C_ + t] : 0.f;
    }
}

// K1: initial centroids = mean over each 16x16 tile. 1 block per (b,s).
__global__ __launch_bounds__(256) void k_cent0(const float* __restrict__ x,
                                               float* __restrict__ cent0) {
    const int blk = blockIdx.x;            // b*S_ + s
    const int b = blk >> 8, s = blk & 255;
    const int sy = s >> 4, sx = s & 15;
    const int t = threadIdx.x;
    const int w = t >> 6, lane = t & 63;
    const int py = sy * 16 + (t >> 4), pxc = sx * 16 + (t & 15);
    const float* xb = x + (size_t)b * C_ * N_ + py * W_ + pxc;
    __shared__ float acc[C_][4];
    #pragma unroll
    for (int c = 0; c < C_; ++c) {
        const float v = wave_sum(xb[c * N_]);
        if (lane == 0) acc[c][w] = v;
    }
    __syncthreads();
    if (t < C_)
        cent0[(size_t)blk * C_ + t] =
            (acc[t][0] + acc[t][1] + acc[t][2] + acc[t][3]) * (1.0f / 256.0f);
}

// K2: iteration 0, atomic-free. Phase A: stage x, per-pixel aff[9] vs cent0.
// Phase B: block partials num[k][c] = sum_p aff[k][p]*x[c][p] as LDS dots;
// den[k] via 9 wave_sums. Partials -> part[blk][PSTR]; gathered by k_cent1.
__global__ __launch_bounds__(256) void k_part(const float* __restrict__ x,
                                              const float* __restrict__ cent0,
                                              float* __restrict__ part) {
    const int blk = blockIdx.x;
    const int b = blk >> 8, s = blk & 255;
    const int sy = s >> 4, sx = s & 15;
    const int t = threadIdx.x;
    const int w = t >> 6, lane = t & 63;
    __shared__ float cl[9][C_];
    __shared__ float xsh[C_][PADP];
    __shared__ float affs[9][PADP];
    __shared__ float lden[4][9];
    load_cl(cent0, b, sy, sx, t, cl);
    stage_tile(x, b, sy, sx, t, xsh);
    __syncthreads();
    float xv[C_];
    #pragma unroll
    for (int c = 0; c < C_; ++c) xv[c] = xsh[c][t];   // conflict-free column read
    float aff[9];
    compute_aff(xv, cl, sy, sx, aff);
    #pragma unroll
    for (int k = 0; k < 9; ++k) {
        affs[k][t] = aff[k];
        const float v = wave_sum(aff[k]);
        if (lane == 0) lden[w][k] = v;
    }
    __syncthreads();
    // Phase B: outputs t = k*32+c for k=0..7; t<32 also does k=8.
    {
        const int k = t >> 5, c = t & 31;
        float acc2 = 0.f;
        #pragma unroll 4
        for (int p = 0; p < 256; p += 4) {
            const float4 a = *(const float4*)&affs[k][p];     // broadcast
            const float4 xc = *(const float4*)&xsh[c][p];
            acc2 += a.x * xc.x + a.y * xc.y + a.z * xc.z + a.w * xc.w;
        }
        part[(size_t)blk * PSTR + t] = acc2;
    }
    if (t < 32) {
        float acc2 = 0.f;
        #pragma unroll 4
        for (int p = 0; p < 256; p += 4) {
            const float4 a = *(const float4*)&affs[8][p];
            const float4 xc = *(const float4*)&xsh[t][p];
            acc2 += a.x * xc.x + a.y * xc.y + a.z * xc.z + a.w * xc.w;
        }
        part[(size_t)blk * PSTR + 256 + t] = acc2;
    }
    if (t < 9)
        part[(size_t)blk * PSTR + 288 + t] =
            lden[0][t] + lden[1][t] + lden[2][t] + lden[3][t];
}

// K3: gather partials -> cent1[b,s,c] = num/(den+1e-16).
__global__ __launch_bounds__(256) void k_cent1(const float* __restrict__ part,
                                               float* __restrict__ cent1) {
    const int g = blockIdx.x * 256 + threadIdx.x;   // < B*S*C = 32768
    const int c = g & 31, s = (g >> 5) & 255, b = g >> 13;
    const int sy = s >> 4, sx = s & 15;
    float num = 0.f, den = 0.f;
    #pragma unroll
    for (int k = 0; k < 9; ++k) {
        const int syp = sy - (k / 3 - 1), sxp = sx - (k % 3 - 1);
        if ((syp >= 0) & (syp < NH_) & (sxp >= 0) & (sxp < NH_)) {
            const size_t base = (size_t)(b * S_ + syp * NH_ + sxp) * PSTR;
            num += part[base + k * 32 + c];
            den += part[base + 288 + k];
        }
    }
    cent1[g] = num / (den + 1e-16f);
}

// K4: iteration 1 affinities vs cent1 -> compact aff9 (B,9,N).
// Stores via LDS transpose so every global store is 16B.
__global__ __launch_bounds__(256) void k_aff9(const float* __restrict__ x,
                                              const float* __restrict__ cent1,
                                              float* __restrict__ aff9) {
    const int blk = blockIdx.x;
    const int b = blk >> 8, s = blk & 255;
    const int sy = s >> 4, sx = s & 15;
    const int t = threadIdx.x;
    __shared__ float cl[9][C_];
    __shared__ float xsh[C_][PADP];
    __shared__ float affs[9][PADP];
    load_cl(cent1, b, sy, sx, t, cl);
    stage_tile(x, b, sy, sx, t, xsh);
    __syncthreads();
    float xv[C_];
    #pragma unroll
    for (int c = 0; c < C_; ++c) xv[c] = xsh[c][t];
    float aff[9];
    compute_aff(xv, cl, sy, sx, aff);
    #pragma unroll
    for (int k = 0; k < 9; ++k) affs[k][t] = aff[k];
    __syncthreads();
    // 576 float4 stores (9 planes x 64), 16B each, contiguous within a row.
    #pragma unroll
    for (int i = 0; i < 3; ++i) {
        const int idx = i * 256 + t;
        if (idx < 576) {
            const int k = idx >> 6, j4 = idx & 63;
            const int py = j4 >> 2, px4 = (j4 & 3) * 4;
            const float4 v = *(const float4*)&affs[k][j4 * 4];
            const int n = (sy * 16 + py) * W_ + sx * 16 + px4;
            *(float4*)(aff9 + ((size_t)(b * 9 + k) << 16) + n) = v;
        }
    }
}

// K5: dense expansion (B,S,N) + scalar S. 8 float4/thread, 8192 blocks.
__global__ __launch_bounds__(256) void k_write(const float* __restrict__ aff9,
                                               float* __restrict__ out) {
    const int t = threadIdx.x;
    const int bs = blockIdx.x >> 3;            // plane id: b*256+s
    const int b = bs >> 8, s = bs & 255;
    const int sdy = (s >> 4) + 1, sdx = (s & 15) + 1;
    const int qb = (blockIdx.x & 7) * 2048 + t;
    const float* plane = aff9 + ((size_t)b * 9 << 16);
    float4* outp = (float4*)out + ((size_t)bs << 14);
    #pragma unroll
    for (int i = 0; i < 8; ++i) {
        const int q = qb + i * 256;            // float4 index within plane
        const int ly = q >> 10;
        const int lx = (q >> 2) & 15;          // constant over the 4 pixels
        const int dy = sdy - ly, dx = sdx - lx;
        float4 v = make_float4(0.f, 0.f, 0.f, 0.f);
        if (((unsigned)dy <= 2u) & ((unsigned)dx <= 2u))
            v = *(const float4*)(plane + ((size_t)(dy * 3 + dx) << 16) + (q << 2));
        outp[q] = v;
    }
    if ((blockIdx.x | t) == 0) out[(size_t)B_ * S_ * N_] = 256.0f;  // output 1: S
}

extern "C" void kernel_launch(void* const* d_in, const int* in_sizes, int n_in,
                              void* d_out, int out_size, void* d_ws, size_t ws_size,
                              hipStream_t stream) {
    const float* x = (const float*)d_in[0];
    float* ws = (float*)d_ws;
    // ws layout (floats): cent0[32768] | part[1024*304] | cent1[32768] | aff9[2359296]
    float* cent0 = ws;
    float* part  = ws + 32768;
    float* cent1 = ws + 32768 + 1024 * PSTR;
    float* aff9  = ws + 32768 + 1024 * PSTR + 32768;   // 16B-aligned
    float* out   = (float*)d_out;

    hipLaunchKernelGGL(k_cent0, dim3(B_ * S_), dim3(256), 0, stream, x, cent0);
    hipLaunchKernelGGL(k_part,  dim3(B_ * S_), dim3(256), 0, stream, x, cent0, part);
    hipLaunchKernelGGL(k_cent1, dim3(B_ * S_ * C_ / 256), dim3(256), 0, stream, part, cent1);
    hipLaunchKernelGGL(k_aff9,  dim3(B_ * S_), dim3(256), 0, stream, x, cent1, aff9);
    hipLaunchKernelGGL(k_write, dim3(B_ * S_ * 8), dim3(256), 0, stream, aff9, out);
}

// Round 4
// 320.772 us; speedup vs baseline: 1.1268x; 1.1268x over previous
//
#include <hip/hip_runtime.h>

// SSN soft-superpixel assignment. Fixed shapes: x (4,32,256,256) fp32, s=16.
// M = 0 -> the two grid channels are identically zero everywhere (px and
// centroids), so they cancel in distances and updates; drop them (C=32).
//
// 3-kernel pipeline. The dense output (B,S,N) is 97% zeros that depend on
// nothing: zero-fill is fused into k_part/k_aff9 as dependency-free stores
// that overlap their LDS-bound compute; the 9-neighborhood values are
// scattered directly from k_aff9's LDS tile (no aff9 buffer, no k_write).
#define B_  4
#define C_  32
#define W_  256
#define N_  65536   // H*W
#define NH_ 16      // 16x16 superpixel grid
#define S_  256
#define PADP 260    // padded pixel stride for LDS [c][p] / [k][p] tiles
#define PSTR 304    // per-block partial stride: 288 num + 9 den + pad

__device__ __forceinline__ float wave_sum(float v) {
    v += __shfl_down(v, 32);
    v += __shfl_down(v, 16);
    v += __shfl_down(v, 8);
    v += __shfl_down(v, 4);
    v += __shfl_down(v, 2);
    v += __shfl_down(v, 1);
    return v;  // lane 0 holds the 64-lane sum
}

// Stage this block's 16x16x32 tile of x into xsh[c][p] (p = py*16+px),
// coalesced float4: idx -> channel c = idx>>6, f4 p4 = idx&63.
__device__ __forceinline__ void stage_tile(const float* __restrict__ x,
                                           int b, int sy, int sx, int t,
                                           float (*xsh)[PADP]) {
    const float* base = x + (size_t)b * C_ * N_ + (sy * 16) * W_ + sx * 16;
    #pragma unroll
    for (int i = 0; i < 8; ++i) {
        const int idx = i * 256 + t;
        const int c = idx >> 6, p4 = idx & 63;
        const float4 v = *(const float4*)(base + (size_t)c * N_ + (p4 >> 2) * W_ + (p4 & 3) * 4);
        *(float4*)&xsh[c][p4 * 4] = v;
    }
}

// Per-pixel softmax over the 3x3 superpixel neighborhood (cl[k] zeroed for
// invalid k; masked to aff=0 anyway). Equivalent to ref softmax(-dist)+mask.
__device__ __forceinline__ void compute_aff(const float xv[C_], const float (*cl)[C_],
                                            int sy, int sx, float aff[9]) {
    float dist[9];
    #pragma unroll
    for (int k = 0; k < 9; ++k) {
        const int ny = sy + k / 3 - 1, nx = sx + k % 3 - 1;
        const bool valid = (ny >= 0) & (ny < NH_) & (nx >= 0) & (nx < NH_);
        float d = 0.f;
        #pragma unroll
        for (int c4 = 0; c4 < C_ / 4; ++c4) {
            const float4 cv = *(const float4*)&cl[k][c4 * 4];   // LDS broadcast
            const float d0 = xv[c4 * 4 + 0] - cv.x;
            const float d1 = xv[c4 * 4 + 1] - cv.y;
            const float d2 = xv[c4 * 4 + 2] - cv.z;
            const float d3 = xv[c4 * 4 + 3] - cv.w;
            d += d0 * d0 + d1 * d1 + d2 * d2 + d3 * d3;
        }
        dist[k] = valid ? d : 1e30f;
    }
    float mind = dist[0];
    #pragma unroll
    for (int k = 1; k < 9; ++k) mind = fminf(mind, dist[k]);
    float sum = 0.f;
    #pragma unroll
    for (int k = 0; k < 9; ++k) {
        const float e = (dist[k] < 1e29f) ? __expf(mind - dist[k]) : 0.f;
        aff[k] = e;
        sum += e;
    }
    const float inv = 1.f / sum;   // home superpixel always valid
    #pragma unroll
    for (int k = 0; k < 9; ++k) aff[k] *= inv;
}

// K1: initial centroids = tile means. Wave w handles channels i*4+w; 64 lanes
// cover the 64 float4 of one channel tile. Coalesced 1KB/wave loads.
__global__ __launch_bounds__(256) void k_cent0(const float* __restrict__ x,
                                               float* __restrict__ cent0) {
    const int blk = blockIdx.x;            // b*S_ + s
    const int b = blk >> 8, s = blk & 255;
    const int sy = s >> 4, sx = s & 15;
    const int t = threadIdx.x;
    const int w = t >> 6, lane = t & 63;
    const float* base = x + (size_t)b * C_ * N_ + (sy * 16) * W_ + sx * 16;
    #pragma unroll
    for (int i = 0; i < 8; ++i) {
        const int c = i * 4 + w;
        const float4 v = *(const float4*)(base + (size_t)c * N_ + (lane >> 2) * W_ + (lane & 3) * 4);
        const float sm = wave_sum(v.x + v.y + v.z + v.w);
        if (lane == 0) cent0[(size_t)blk * C_ + c] = sm * (1.0f / 256.0f);
    }
}

// K2: iteration 0 partials + zero-fill of output plane rows 0..127.
// Phase A: stage x, per-pixel aff[9] vs cent0 (cl from global, 288 entries).
// Phase B: num[k][c] = sum_p aff[k][p]*x[c][p] as LDS dots; den via wave_sums.
__global__ __launch_bounds__(256) void k_part(const float* __restrict__ x,
                                              const float* __restrict__ cent0,
                                              float* __restrict__ part,
                                              float* __restrict__ out) {
    const int blk = blockIdx.x;
    const int b = blk >> 8, s = blk & 255;
    const int sy = s >> 4, sx = s & 15;
    const int t = threadIdx.x;
    const int w = t >> 6, lane = t & 63;
    __shared__ float cl[9][C_];
    __shared__ float xsh[C_][PADP];
    __shared__ float affs[9][PADP];
    __shared__ float lden[4][9];
    {   // cl fill: k=0..7 by all, k=8 by t<32
        const int k = t >> 5, c = t & 31;
        const int ny = sy + k / 3 - 1, nx = sx + k % 3 - 1;
        const bool valid = (ny >= 0) & (ny < NH_) & (nx >= 0) & (nx < NH_);
        cl[k][c] = valid ? cent0[(size_t)(b * S_ + ny * NH_ + nx) * C_ + c] : 0.f;
    }
    if (t < 32) {
        const int ny = sy + 1, nx = sx + 1;
        const bool valid = (ny < NH_) & (nx < NH_);
        cl[8][t] = valid ? cent0[(size_t)(b * S_ + ny * NH_ + nx) * C_ + t] : 0.f;
    }
    stage_tile(x, b, sy, sx, t, xsh);
    {   // Zero-fill half A (plane rows 0..127), skipping the 3x3 tile
        // neighborhood (written by k_aff9's scatter). Fire-and-forget stores
        // that overlap the LDS compute below.
        const float4 z = make_float4(0.f, 0.f, 0.f, 0.f);
        float4* plane = (float4*)out + ((size_t)blk << 14);
        #pragma unroll
        for (int i = 0; i < 32; ++i) {
            const int q = i * 256 + t;           // f4 index, rows 0..127
            const int ty = q >> 10;              // pixel-row tile
            const int tx = (q >> 2) & 15;        // col tile
            if (((unsigned)(ty - sy + 1) > 2u) | ((unsigned)(tx - sx + 1) > 2u))
                plane[q] = z;
        }
    }
    __syncthreads();
    float xv[C_];
    #pragma unroll
    for (int c = 0; c < C_; ++c) xv[c] = xsh[c][t];   // conflict-free
    float aff[9];
    compute_aff(xv, cl, sy, sx, aff);
    #pragma unroll
    for (int k = 0; k < 9; ++k) {
        affs[k][t] = aff[k];
        const float v = wave_sum(aff[k]);
        if (lane == 0) lden[w][k] = v;
    }
    __syncthreads();
    {   // Phase B: outputs t = k*32+c for k=0..7; t<32 also k=8.
        const int k = t >> 5, c = t & 31;
        float acc = 0.f;
        #pragma unroll 4
        for (int p = 0; p < 256; p += 4) {
            const float4 a = *(const float4*)&affs[k][p];
            const float4 xc = *(const float4*)&xsh[c][p];
            acc += a.x * xc.x + a.y * xc.y + a.z * xc.z + a.w * xc.w;
        }
        part[(size_t)blk * PSTR + t] = acc;
    }
    if (t < 32) {
        float acc = 0.f;
        #pragma unroll 4
        for (int p = 0; p < 256; p += 4) {
            const float4 a = *(const float4*)&affs[8][p];
            const float4 xc = *(const float4*)&xsh[t][p];
            acc += a.x * xc.x + a.y * xc.y + a.z * xc.z + a.w * xc.w;
        }
        part[(size_t)blk * PSTR + 256 + t] = acc;
    }
    if (t < 9)
        part[(size_t)blk * PSTR + 288 + t] =
            lden[0][t] + lden[1][t] + lden[2][t] + lden[3][t];
}

// cent1[b, (ny,nx), c] = num/(den+1e-16), gathered from the 9 source blocks'
// partials (part is L2-hot, 1.2 MB).
__device__ __forceinline__ float gather_cent1(const float* __restrict__ part,
                                              int b, int ny, int nx, int c) {
    float num = 0.f, den = 0.f;
    #pragma unroll
    for (int k2 = 0; k2 < 9; ++k2) {
        const int syp = ny - (k2 / 3 - 1), sxp = nx - (k2 % 3 - 1);
        if ((syp >= 0) & (syp < NH_) & (sxp >= 0) & (sxp < NH_)) {
            const size_t base = (size_t)(b * S_ + syp * NH_ + sxp) * PSTR;
            num += part[base + k2 * 32 + c];
            den += part[base + 288 + k2];
        }
    }
    return num / (den + 1e-16f);
}

// K3: iteration-1 affinities vs cent1 (gathered in-kernel) + zero-fill of
// plane rows 128..255 + direct scatter of the 9-neighborhood values from LDS.
__global__ __launch_bounds__(256) void k_aff9(const float* __restrict__ x,
                                              const float* __restrict__ part,
                                              float* __restrict__ out) {
    const int blk = blockIdx.x;
    const int b = blk >> 8, s = blk & 255;
    const int sy = s >> 4, sx = s & 15;
    const int t = threadIdx.x;
    __shared__ float cl[9][C_];
    __shared__ float xsh[C_][PADP];
    __shared__ float affs[9][PADP];
    {   // cl = cent1 of the 9 neighbors, computed on the fly
        const int k = t >> 5, c = t & 31;
        const int ny = sy + k / 3 - 1, nx = sx + k % 3 - 1;
        const bool valid = (ny >= 0) & (ny < NH_) & (nx >= 0) & (nx < NH_);
        cl[k][c] = valid ? gather_cent1(part, b, ny, nx, c) : 0.f;
    }
    if (t < 32) {
        const int ny = sy + 1, nx = sx + 1;
        const bool valid = (ny < NH_) & (nx < NH_);
        cl[8][t] = valid ? gather_cent1(part, b, ny, nx, t) : 0.f;
    }
    stage_tile(x, b, sy, sx, t, xsh);
    {   // Zero-fill half B (plane rows 128..255), same exclusion.
        const float4 z = make_float4(0.f, 0.f, 0.f, 0.f);
        float4* plane = (float4*)out + ((size_t)blk << 14);
        #pragma unroll
        for (int i = 32; i < 64; ++i) {
            const int q = i * 256 + t;
            const int ty = q >> 10;
            const int tx = (q >> 2) & 15;
            if (((unsigned)(ty - sy + 1) > 2u) | ((unsigned)(tx - sx + 1) > 2u))
                plane[q] = z;
        }
    }
    __syncthreads();
    float xv[C_];
    #pragma unroll
    for (int c = 0; c < C_; ++c) xv[c] = xsh[c][t];
    float aff[9];
    compute_aff(xv, cl, sy, sx, aff);
    #pragma unroll
    for (int k = 0; k < 9; ++k) affs[k][t] = aff[k];
    __syncthreads();
    // Scatter: for valid neighbor k, write this tile's 16x16 values into
    // plane s'=(ny,nx) — 576 float4 total (64B row-segments).
    #pragma unroll
    for (int i = 0; i < 3; ++i) {
        const int idx = i * 256 + t;
        if (idx < 576) {
            const int k = idx >> 6, j4 = idx & 63;
            const int ny = sy + k / 3 - 1, nx = sx + k % 3 - 1;
            if ((ny >= 0) & (ny < NH_) & (nx >= 0) & (nx < NH_)) {
                const float4 v = *(const float4*)&affs[k][j4 * 4];
                const int gq = (sy * 16 + (j4 >> 2)) * 64 + sx * 4 + (j4 & 3);
                ((float4*)out)[((size_t)(b * S_ + ny * NH_ + nx) << 14) + gq] = v;
            }
        }
    }
    if ((blk | t) == 0) out[(size_t)B_ * S_ * N_] = 256.0f;  // output 1: S
}

extern "C" void kernel_launch(void* const* d_in, const int* in_sizes, int n_in,
                              void* d_out, int out_size, void* d_ws, size_t ws_size,
                              hipStream_t stream) {
    const float* x = (const float*)d_in[0];
    float* ws = (float*)d_ws;
    // ws layout (floats): cent0[32768] | part[1024*304]
    float* cent0 = ws;
    float* part  = ws + 32768;
    float* out   = (float*)d_out;

    hipLaunchKernelGGL(k_cent0, dim3(B_ * S_), dim3(256), 0, stream, x, cent0);
    hipLaunchKernelGGL(k_part,  dim3(B_ * S_), dim3(256), 0, stream, x, cent0, part, out);
    hipLaunchKernelGGL(k_aff9,  dim3(B_ * S_), dim3(256), 0, stream, x, part, out);
}